// Round 1
// baseline (618.046 us; speedup 1.0000x reference)
//
#include <hip/hip_runtime.h>

#define B_N 4096
#define D_IN 1024
#define D_F 256
#define MK 80
#define LOG2PI 1.8378770664093453f

typedef float f32x4 __attribute__((ext_vector_type(4)));
typedef short bf16x8 __attribute__((ext_vector_type(8)));
typedef float float4_ __attribute__((ext_vector_type(4)));

__device__ __forceinline__ unsigned short f2bf(float f) {
    unsigned u = __float_as_uint(f);
    u += 0x7fffu + ((u >> 16) & 1u);
    return (unsigned short)(u >> 16);
}
__device__ __forceinline__ float bf2f(unsigned short h) {
    return __uint_as_float(((unsigned)h) << 16);
}
__device__ __forceinline__ void gload_lds16(const void* g, void* l) {
    __builtin_amdgcn_global_load_lds((const __attribute__((address_space(1))) void*)g,
                                     (__attribute__((address_space(3))) void*)l, 16, 0, 0);
}

// ---------------- K1: x (f32) -> xb (bf16) ----------------
__global__ __launch_bounds__(256) void k_cvt_x(const float* __restrict__ x,
                                               unsigned short* __restrict__ xb) {
    int idx = blockIdx.x * 256 + threadIdx.x;
    int stride = gridDim.x * 256;
    int n4 = (B_N * D_IN) / 4;
    for (int i = idx; i < n4; i += stride) {
        float4_ v = ((const float4_*)x)[i];
        ushort4 o;
        o.x = f2bf(v.x); o.y = f2bf(v.y); o.z = f2bf(v.z); o.w = f2bf(v.w);
        ((ushort4*)xb)[i] = o;
    }
}

// ---------------- K2: W [1024][256] f32 -> Wt [256][1024] bf16 ----------------
__global__ __launch_bounds__(256) void k_tw(const float* __restrict__ W,
                                            unsigned short* __restrict__ wt) {
    __shared__ unsigned short t[64][65];
    int k0 = blockIdx.x * 64, n0 = blockIdx.y * 64;
    int r = threadIdx.x / 64, c = threadIdx.x % 64;
    #pragma unroll
    for (int rr = r; rr < 64; rr += 4)
        t[rr][c] = f2bf(W[(size_t)(k0 + rr) * D_F + n0 + c]);
    __syncthreads();
    #pragma unroll
    for (int rr = r; rr < 64; rr += 4)
        wt[(size_t)(n0 + rr) * D_IN + k0 + c] = t[c][rr];
}

// ---------------- K3: softmax weights + logdet ----------------
__global__ __launch_bounds__(64) void k_stats(const float* __restrict__ covs,
                                              const float* __restrict__ wts,
                                              float* __restrict__ wmix,
                                              float* __restrict__ ldet) {
    int mk = blockIdx.x;
    int l = threadIdx.x;
    const float* Lm = covs + (size_t)mk * D_F * D_F;
    float s = 0.0f;
    for (int i = l; i < D_F; i += 64) s += logf(Lm[(size_t)i * D_F + i]);
    for (int off = 32; off; off >>= 1) s += __shfl_down(s, off);
    if (l == 0) {
        ldet[mk] = s;
        int m = mk / 8, k = mk % 8;
        float mx = -1e30f;
        for (int j = 0; j < 8; j++) mx = fmaxf(mx, wts[m * 8 + j]);
        float sum = 0.0f;
        for (int j = 0; j < 8; j++) sum += expf(wts[m * 8 + j] - mx);
        wmix[mk] = expf(wts[m * 8 + k] - mx) / sum;
    }
}

// ---------------- K5: invert 80 lower-triangular L (fp32 recurrence, bf16 out) ----
// grid (MK, 4): one block per (component, 64-column panel). 256 threads (4 waves).
__global__ __launch_bounds__(256) void k_inv(const float* __restrict__ covs,
                                             unsigned short* __restrict__ linv) {
    int mk = blockIdx.x, p = blockIdx.y;
    int j0 = p * 64;
    const float* Lm = covs + (size_t)mk * D_F * D_F;
    unsigned short* Xout = linv + (size_t)mk * D_F * D_F;
    __shared__ unsigned short X[256][64];  // bf16 panel, 32 KB
    __shared__ float row[256];
    __shared__ float part[4][64];
    __shared__ float dinv[256];
    int tid = threadIdx.x, w = tid >> 6, l = tid & 63;
    dinv[tid] = 1.0f / Lm[(size_t)tid * D_F + tid];
    // zero rows above the panel's diagonal band (upper triangle in these cols)
    for (int i = w; i < j0; i += 4)
        Xout[(size_t)i * D_F + j0 + l] = 0;
    __syncthreads();
    for (int i = j0; i < 256; ++i) {
        for (int k = j0 + tid; k < i; k += 256) row[k - j0] = Lm[(size_t)i * D_F + k];
        __syncthreads();
        float s = 0.0f;
        for (int k = j0 + w; k < i; k += 4) s += row[k - j0] * bf2f(X[k - j0][l]);
        part[w][l] = s;
        __syncthreads();
        if (w == 0) {
            float sum = part[0][l] + part[1][l] + part[2][l] + part[3][l];
            float delta = (j0 + l == i) ? 1.0f : 0.0f;
            float xv = (delta - sum) * dinv[i];
            unsigned short xb16 = f2bf(xv);
            X[i - j0][l] = xb16;
            Xout[(size_t)i * D_F + j0 + l] = xb16;
        }
        __syncthreads();
    }
}

// ---------------- K6: c[mk][i] = sum_d Linv_bf16[mk][i][d] * mu[mk][d] (fp32) ----
__global__ __launch_bounds__(256) void k_cvec(const unsigned short* __restrict__ linv,
                                              const float* __restrict__ means,
                                              float* __restrict__ cvec) {
    int mk = blockIdx.x, tid = threadIdx.x;
    __shared__ float mu[D_F];
    mu[tid] = means[(size_t)mk * D_F + tid];
    __syncthreads();
    const unsigned short* Lr = linv + (size_t)mk * D_F * D_F + (size_t)tid * D_F;
    float s = 0.0f;
    #pragma unroll 4
    for (int d = 0; d < D_F; d += 4) {
        ushort4 a = *(const ushort4*)(Lr + d);
        s += bf2f(a.x) * mu[d] + bf2f(a.y) * mu[d + 1] +
             bf2f(a.z) * mu[d + 2] + bf2f(a.w) * mu[d + 3];
    }
    cvec[(size_t)mk * D_F + tid] = s;
}

// ---------------- K4: extractor GEMM  F = relu(x @ W + b) -> bf16 [4096][256] ----
// 64x64 tile, BK=64, 256 threads (4 waves, 2x2), grid (64, 4)
__global__ __launch_bounds__(256) void k_feat(const unsigned short* __restrict__ xb,
                                              const unsigned short* __restrict__ wt,
                                              const float* __restrict__ bias,
                                              unsigned short* __restrict__ fb) {
    __shared__ unsigned short As[64][64];
    __shared__ unsigned short Bs[64][64];
    int b0 = blockIdx.x * 64;
    int n0 = blockIdx.y * 64;
    int tid = threadIdx.x, w = tid >> 6, l = tid & 63;
    int wm = w >> 1, wn = w & 1;
    f32x4 acc[2][2] = {};
    for (int k0 = 0; k0 < D_IN; k0 += 64) {
        #pragma unroll
        for (int it = 0; it < 2; ++it) {
            int o16 = tid + it * 256;
            int r = o16 >> 3, c8 = o16 & 7;
            gload_lds16(xb + (size_t)(b0 + r) * D_IN + k0 + c8 * 8, &As[0][0] + o16 * 8);
            gload_lds16(wt + (size_t)(n0 + r) * D_IN + k0 + c8 * 8, &Bs[0][0] + o16 * 8);
        }
        __syncthreads();
        #pragma unroll
        for (int ks = 0; ks < 2; ++ks) {
            int kb = ks * 32 + (l >> 4) * 8;
            bf16x8 af[2], bg[2];
            #pragma unroll
            for (int mi = 0; mi < 2; ++mi)
                af[mi] = *(const bf16x8*)&As[wm * 32 + mi * 16 + (l & 15)][kb];
            #pragma unroll
            for (int ni = 0; ni < 2; ++ni)
                bg[ni] = *(const bf16x8*)&Bs[wn * 32 + ni * 16 + (l & 15)][kb];
            #pragma unroll
            for (int mi = 0; mi < 2; ++mi)
                #pragma unroll
                for (int ni = 0; ni < 2; ++ni)
                    acc[mi][ni] = __builtin_amdgcn_mfma_f32_16x16x32_bf16(
                        af[mi], bg[ni], acc[mi][ni], 0, 0, 0);
        }
        __syncthreads();
    }
    #pragma unroll
    for (int mi = 0; mi < 2; ++mi)
        #pragma unroll
        for (int ni = 0; ni < 2; ++ni) {
            int d = n0 + wn * 32 + ni * 16 + (l & 15);
            float bia = bias[d];
            #pragma unroll
            for (int r = 0; r < 4; ++r) {
                int b = b0 + wm * 32 + mi * 16 + (l >> 4) * 4 + r;
                float v = fmaxf(acc[mi][ni][r] + bia, 0.0f);
                fb[(size_t)b * D_F + d] = f2bf(v);
            }
        }
}

// ---------------- K7: big GEMM Z = Linv @ F^T, fused quad/out epilogue ----------
// BM=256 (all i of one component), BN=128 (batch), BK=64. 512 threads = 8 waves (4x2).
__global__ __launch_bounds__(512) void k_gmm(const unsigned short* __restrict__ linv,
                                             const unsigned short* __restrict__ fb,
                                             const float* __restrict__ cvec,
                                             const float* __restrict__ wmix,
                                             const float* __restrict__ ldet,
                                             float* __restrict__ out) {
    __shared__ unsigned short As[256][64];  // 32 KB
    __shared__ unsigned short Bs[128][64];  // 16 KB
    __shared__ float cb[D_F];
    __shared__ float qpart[4][128];
    int mk = blockIdx.x;
    int b0 = blockIdx.y * 128;
    int tid = threadIdx.x, w = tid >> 6, l = tid & 63;
    int wm = w >> 1, wn = w & 1;
    const unsigned short* Ab = linv + (size_t)mk * D_F * D_F;
    if (tid < D_F) cb[tid] = cvec[(size_t)mk * D_F + tid];
    f32x4 acc[4][4] = {};
    for (int k0 = 0; k0 < D_F; k0 += 64) {
        #pragma unroll
        for (int it = 0; it < 4; ++it) {
            int o16 = tid + it * 512;
            int r = o16 >> 3, c8 = o16 & 7;
            gload_lds16(Ab + (size_t)r * D_F + k0 + c8 * 8, &As[0][0] + o16 * 8);
        }
        #pragma unroll
        for (int it = 0; it < 2; ++it) {
            int o16 = tid + it * 512;
            int r = o16 >> 3, c8 = o16 & 7;
            gload_lds16(fb + (size_t)(b0 + r) * D_F + k0 + c8 * 8, &Bs[0][0] + o16 * 8);
        }
        __syncthreads();
        #pragma unroll
        for (int ks = 0; ks < 2; ++ks) {
            int kb = ks * 32 + (l >> 4) * 8;
            bf16x8 af[4], bg[4];
            #pragma unroll
            for (int mi = 0; mi < 4; ++mi)
                af[mi] = *(const bf16x8*)&As[wm * 64 + mi * 16 + (l & 15)][kb];
            #pragma unroll
            for (int ni = 0; ni < 4; ++ni)
                bg[ni] = *(const bf16x8*)&Bs[wn * 64 + ni * 16 + (l & 15)][kb];
            #pragma unroll
            for (int mi = 0; mi < 4; ++mi)
                #pragma unroll
                for (int ni = 0; ni < 4; ++ni)
                    acc[mi][ni] = __builtin_amdgcn_mfma_f32_16x16x32_bf16(
                        af[mi], bg[ni], acc[mi][ni], 0, 0, 0);
        }
        __syncthreads();
    }
    // epilogue: quad = sum_i (z - c_i)^2, reduce over i
    float p[4] = {0, 0, 0, 0};
    #pragma unroll
    for (int mi = 0; mi < 4; ++mi) {
        int ibase = wm * 64 + mi * 16 + ((l >> 4) << 2);
        #pragma unroll
        for (int r = 0; r < 4; ++r) {
            float cv = cb[ibase + r];
            #pragma unroll
            for (int ni = 0; ni < 4; ++ni) {
                float z = acc[mi][ni][r] - cv;
                p[ni] += z * z;
            }
        }
    }
    #pragma unroll
    for (int ni = 0; ni < 4; ++ni) {
        p[ni] += __shfl_xor(p[ni], 16);
        p[ni] += __shfl_xor(p[ni], 32);
    }
    if (l < 16) {
        #pragma unroll
        for (int ni = 0; ni < 4; ++ni)
            qpart[wm][wn * 64 + ni * 16 + l] = p[ni];
    }
    __syncthreads();
    if (tid < 128) {
        float q = qpart[0][tid] + qpart[1][tid] + qpart[2][tid] + qpart[3][tid];
        float lp = -0.5f * (q + (float)D_F * LOG2PI) - ldet[mk];
        out[(size_t)(b0 + tid) * MK + mk] = wmix[mk] * lp;
    }
}

extern "C" void kernel_launch(void* const* d_in, const int* in_sizes, int n_in,
                              void* d_out, int out_size, void* d_ws, size_t ws_size,
                              hipStream_t stream) {
    const float* x     = (const float*)d_in[0];
    const float* W     = (const float*)d_in[1];
    const float* bias  = (const float*)d_in[2];
    const float* means = (const float*)d_in[3];
    const float* covs  = (const float*)d_in[4];
    const float* wts   = (const float*)d_in[5];
    float* out = (float*)d_out;

    char* ws = (char*)d_ws;
    unsigned short* xb   = (unsigned short*)(ws);                    // 8 MB
    unsigned short* wt   = (unsigned short*)(ws + 8388608);          // 0.5 MB
    unsigned short* fb   = (unsigned short*)(ws + 8912896);          // 2 MB
    unsigned short* linv = (unsigned short*)(ws + 11010048);         // 10.5 MB
    float* cvec = (float*)(ws + 21495808);                           // 80 KB
    float* wmix = (float*)(ws + 21577728);                           // 320 B
    float* ldet = (float*)(ws + 21578048);                           // 320 B

    k_cvt_x<<<dim3(2048), dim3(256), 0, stream>>>(x, xb);
    k_tw<<<dim3(16, 4), dim3(256), 0, stream>>>(W, wt);
    k_stats<<<dim3(MK), dim3(64), 0, stream>>>(covs, wts, wmix, ldet);
    k_inv<<<dim3(MK, 4), dim3(256), 0, stream>>>(covs, linv);
    k_feat<<<dim3(64, 4), dim3(256), 0, stream>>>(xb, wt, bias, fb);
    k_cvec<<<dim3(MK), dim3(256), 0, stream>>>(linv, means, cvec);
    k_gmm<<<dim3(MK, 32), dim3(512), 0, stream>>>(linv, fb, cvec, wmix, ldet, out);
}

// Round 2
// 177.039 us; speedup vs baseline: 3.4910x; 3.4910x over previous
//
#include <hip/hip_runtime.h>

#define B_N 4096
#define D_IN 1024
#define D_F 256
#define MK 80
#define LOG2PI 1.8378770664093453f
#define XP_S 72  // padded LDS row stride (bf16 elems): 144 B, 16B-aligned, 2-way bank aliasing only

typedef float f32x4 __attribute__((ext_vector_type(4)));
typedef short bf16x8 __attribute__((ext_vector_type(8)));
typedef float float4_ __attribute__((ext_vector_type(4)));
typedef unsigned int u32x4 __attribute__((ext_vector_type(4)));
typedef unsigned short u16x8 __attribute__((ext_vector_type(8)));

__device__ __forceinline__ unsigned short f2bf(float f) {
    unsigned u = __float_as_uint(f);
    u += 0x7fffu + ((u >> 16) & 1u);
    return (unsigned short)(u >> 16);
}
__device__ __forceinline__ float bf2f(unsigned short h) {
    return __uint_as_float(((unsigned)h) << 16);
}
__device__ __forceinline__ void gload_lds16(const void* g, void* l) {
    __builtin_amdgcn_global_load_lds((const __attribute__((address_space(1))) void*)g,
                                     (__attribute__((address_space(3))) void*)l, 16, 0, 0);
}
__device__ __forceinline__ bf16x8 pack8(float4_ a, float4_ b) {
    bf16x8 r;
    r[0] = (short)f2bf(a.x); r[1] = (short)f2bf(a.y);
    r[2] = (short)f2bf(a.z); r[3] = (short)f2bf(a.w);
    r[4] = (short)f2bf(b.x); r[5] = (short)f2bf(b.y);
    r[6] = (short)f2bf(b.z); r[7] = (short)f2bf(b.w);
    return r;
}

// ---------------- K1: x (f32) -> xb (bf16) ----------------
__global__ __launch_bounds__(256) void k_cvt_x(const float* __restrict__ x,
                                               unsigned short* __restrict__ xb) {
    int idx = blockIdx.x * 256 + threadIdx.x;
    int stride = gridDim.x * 256;
    int n4 = (B_N * D_IN) / 4;
    for (int i = idx; i < n4; i += stride) {
        float4_ v = ((const float4_*)x)[i];
        ushort4 o;
        o.x = f2bf(v.x); o.y = f2bf(v.y); o.z = f2bf(v.z); o.w = f2bf(v.w);
        ((ushort4*)xb)[i] = o;
    }
}

// ---------------- K2: W [1024][256] f32 -> Wt [256][1024] bf16 ----------------
__global__ __launch_bounds__(256) void k_tw(const float* __restrict__ W,
                                            unsigned short* __restrict__ wt) {
    __shared__ unsigned short t[64][65];
    int k0 = blockIdx.x * 64, n0 = blockIdx.y * 64;
    int r = threadIdx.x / 64, c = threadIdx.x % 64;
    #pragma unroll
    for (int rr = r; rr < 64; rr += 4)
        t[rr][c] = f2bf(W[(size_t)(k0 + rr) * D_F + n0 + c]);
    __syncthreads();
    #pragma unroll
    for (int rr = r; rr < 64; rr += 4)
        wt[(size_t)(n0 + rr) * D_IN + k0 + c] = t[c][rr];
}

// ---------------- K3: softmax weights + logdet ----------------
__global__ __launch_bounds__(64) void k_stats(const float* __restrict__ covs,
                                              const float* __restrict__ wts,
                                              float* __restrict__ wmix,
                                              float* __restrict__ ldet) {
    int mk = blockIdx.x;
    int l = threadIdx.x;
    const float* Lm = covs + (size_t)mk * D_F * D_F;
    float s = 0.0f;
    for (int i = l; i < D_F; i += 64) s += logf(Lm[(size_t)i * D_F + i]);
    for (int off = 32; off; off >>= 1) s += __shfl_down(s, off);
    if (l == 0) {
        ldet[mk] = s;
        int m = mk / 8, k = mk % 8;
        float mx = -1e30f;
        for (int j = 0; j < 8; j++) mx = fmaxf(mx, wts[m * 8 + j]);
        float sum = 0.0f;
        for (int j = 0; j < 8; j++) sum += expf(wts[m * 8 + j] - mx);
        wmix[mk] = expf(wts[m * 8 + k] - mx) / sum;
    }
}

// ---------------- K5a: invert 64x64 diagonal blocks (fp32 solve, bf16 out) -----
// grid (MK, 4): one single-wave block per (component, diag block I).
// Lane l owns column l of Dinv. Output dinv[mk][I][r][j] row-major bf16
// (upper triangle exact zeros from the recurrence).
__global__ __launch_bounds__(64) void k_dinv(const float* __restrict__ covs,
                                             unsigned short* __restrict__ dinv) {
    int mk = blockIdx.x, I = blockIdx.y;
    int i0 = I * 64;
    __shared__ float Ld[64 * 64];
    __shared__ float Xd[64][65];
    int l = threadIdx.x;
    const float* Cm = covs + (size_t)mk * D_F * D_F + (size_t)i0 * D_F + i0;
    for (int t = l; t < 1024; t += 64) {
        int r = t >> 4, s = t & 15;
        *(f32x4*)&Ld[r * 64 + s * 4] = *(const float4_*)&Cm[(size_t)r * D_F + s * 4];
    }
    __syncthreads();
    for (int i = 0; i < 64; ++i) {
        float s = 0.0f;
        for (int k = 0; k < i; ++k)
            s += Ld[i * 64 + k] * Xd[k][l];  // Ld read is wave-broadcast
        float v = (((i == l) ? 1.0f : 0.0f) - s) / Ld[i * 64 + i];
        Xd[i][l] = v;
    }
    unsigned short* D = dinv + ((size_t)mk * 4 + I) * 4096;
    for (int r = 0; r < 64; ++r)
        D[r * 64 + l] = f2bf(Xd[r][l]);  // coalesced
}

// ---------------- K5b: build Linv column panels via blocked MFMA ---------------
// grid (MK, 4): (component, 64-col panel J). 256 threads = 4 waves.
// Computes X^T tiles: Xt[c][r] = Linv[I*64+r][J*64+c].
// GEMM-1: St[c][r] = sum_K sum_k Xp[K][c][k] * L[I*64+r][K*64+k]   (A=Xp, B=L from global)
// GEMM-2: Xt[I][c][r] = sum_j St[c][j] * (-Dinv[I][r][j])          (A=Sb, B=-dinv from global)
__global__ __launch_bounds__(256) void k_inv_panel(
        const float* __restrict__ covs,
        const unsigned short* __restrict__ dinv,
        unsigned short* __restrict__ linv) {
    int mk = blockIdx.x, J = blockIdx.y;
    int jc0 = J * 64;
    __shared__ unsigned short Xp[4][64][XP_S];  // 73.7 KB
    __shared__ unsigned short Sb[64][XP_S];     // 9.2 KB
    int tid = threadIdx.x, w = tid >> 6, l = tid & 63;
    const float* Cm = covs + (size_t)mk * D_F * D_F;
    unsigned short* Lout = linv + (size_t)mk * D_F * D_F;
    const unsigned short* Dmk = dinv + (size_t)mk * 4 * 4096;

    // 1) zero rows above the panel (upper triangle of these columns)
    for (int t = tid; t < jc0 * 8; t += 256) {
        int r = t >> 3, s = t & 7;
        ((u32x4*)(Lout + (size_t)r * D_F + jc0))[s] = (u32x4){0, 0, 0, 0};
    }
    // 2) Xp[J] = Dinv[J]^T (bf16 scatter) + copy diag block rows to global
    const unsigned short* DJ = Dmk + J * 4096;
    for (int t = tid; t < 4096; t += 256) {
        int r = t >> 6, c = t & 63;
        Xp[J][c][r] = DJ[t];
    }
    for (int t = tid; t < 512; t += 256) {
        int r = t >> 3, s = t & 7;
        ((u32x4*)(Lout + (size_t)(jc0 + r) * D_F + jc0))[s] = ((const u32x4*)(DJ + r * 64))[s];
    }
    __syncthreads();

    for (int I = J + 1; I < 4; ++I) {
        // ---- GEMM-1: St = sum_K Xp[K] x L[I,K]^T ----
        f32x4 acc[4] = {};
        for (int K = J; K < I; ++K) {
            #pragma unroll
            for (int kb = 0; kb < 2; ++kb) {
                bf16x8 af = *(const bf16x8*)&Xp[K][w * 16 + (l & 15)][kb * 32 + (l >> 4) * 8];
                #pragma unroll
                for (int ni = 0; ni < 4; ++ni) {
                    const float* gp = Cm + (size_t)(I * 64 + ni * 16 + (l & 15)) * D_F
                                      + K * 64 + kb * 32 + (l >> 4) * 8;
                    bf16x8 bf = pack8(*(const float4_*)gp, *(const float4_*)(gp + 4));
                    acc[ni] = __builtin_amdgcn_mfma_f32_16x16x32_bf16(af, bf, acc[ni], 0, 0, 0);
                }
            }
        }
        // write St to Sb (bf16)
        #pragma unroll
        for (int ni = 0; ni < 4; ++ni)
            #pragma unroll
            for (int q = 0; q < 4; ++q)
                Sb[w * 16 + ((l >> 4) << 2) + q][ni * 16 + (l & 15)] = f2bf(acc[ni][q]);
        __syncthreads();
        // ---- GEMM-2: Xt[I] = St x (-Dinv[I])^T ----
        f32x4 acc2[4] = {};
        #pragma unroll
        for (int kb = 0; kb < 2; ++kb) {
            bf16x8 af = *(const bf16x8*)&Sb[w * 16 + (l & 15)][kb * 32 + (l >> 4) * 8];
            #pragma unroll
            for (int ni = 0; ni < 4; ++ni) {
                const u16x8* dp = (const u16x8*)(Dmk + (size_t)I * 4096
                                  + (ni * 16 + (l & 15)) * 64 + kb * 32 + (l >> 4) * 8);
                u16x8 dv = *dp ^ (unsigned short)0x8000;  // negate bf16
                bf16x8 bf = __builtin_bit_cast(bf16x8, dv);
                acc2[ni] = __builtin_amdgcn_mfma_f32_16x16x32_bf16(af, bf, acc2[ni], 0, 0, 0);
            }
        }
        // write Xp[I] (LDS, for later row-blocks) + global linv rows
        #pragma unroll
        for (int ni = 0; ni < 4; ++ni)
            #pragma unroll
            for (int q = 0; q < 4; ++q) {
                int c = w * 16 + ((l >> 4) << 2) + q;
                int r = ni * 16 + (l & 15);
                unsigned short hv = f2bf(acc2[ni][q]);
                Xp[I][c][r] = hv;
                Lout[(size_t)(I * 64 + r) * D_F + jc0 + c] = hv;
            }
        __syncthreads();
    }
}

// ---------------- K6: c[mk][i] = sum_d Linv_bf16[mk][i][d] * mu[mk][d] (fp32) ----
__global__ __launch_bounds__(256) void k_cvec(const unsigned short* __restrict__ linv,
                                              const float* __restrict__ means,
                                              float* __restrict__ cvec) {
    int mk = blockIdx.x, tid = threadIdx.x;
    __shared__ float mu[D_F];
    mu[tid] = means[(size_t)mk * D_F + tid];
    __syncthreads();
    const unsigned short* Lr = linv + (size_t)mk * D_F * D_F + (size_t)tid * D_F;
    float s = 0.0f;
    #pragma unroll 4
    for (int d = 0; d < D_F; d += 4) {
        ushort4 a = *(const ushort4*)(Lr + d);
        s += bf2f(a.x) * mu[d] + bf2f(a.y) * mu[d + 1] +
             bf2f(a.z) * mu[d + 2] + bf2f(a.w) * mu[d + 3];
    }
    cvec[(size_t)mk * D_F + tid] = s;
}

// ---------------- K4: extractor GEMM  F = relu(x @ W + b) -> bf16 [4096][256] ----
__global__ __launch_bounds__(256) void k_feat(const unsigned short* __restrict__ xb,
                                              const unsigned short* __restrict__ wt,
                                              const float* __restrict__ bias,
                                              unsigned short* __restrict__ fb) {
    __shared__ unsigned short As[64][64];
    __shared__ unsigned short Bs[64][64];
    int b0 = blockIdx.x * 64;
    int n0 = blockIdx.y * 64;
    int tid = threadIdx.x, w = tid >> 6, l = tid & 63;
    int wm = w >> 1, wn = w & 1;
    f32x4 acc[2][2] = {};
    for (int k0 = 0; k0 < D_IN; k0 += 64) {
        #pragma unroll
        for (int it = 0; it < 2; ++it) {
            int o16 = tid + it * 256;
            int r = o16 >> 3, c8 = o16 & 7;
            gload_lds16(xb + (size_t)(b0 + r) * D_IN + k0 + c8 * 8, &As[0][0] + o16 * 8);
            gload_lds16(wt + (size_t)(n0 + r) * D_IN + k0 + c8 * 8, &Bs[0][0] + o16 * 8);
        }
        __syncthreads();
        #pragma unroll
        for (int ks = 0; ks < 2; ++ks) {
            int kb = ks * 32 + (l >> 4) * 8;
            bf16x8 af[2], bg[2];
            #pragma unroll
            for (int mi = 0; mi < 2; ++mi)
                af[mi] = *(const bf16x8*)&As[wm * 32 + mi * 16 + (l & 15)][kb];
            #pragma unroll
            for (int ni = 0; ni < 2; ++ni)
                bg[ni] = *(const bf16x8*)&Bs[wn * 32 + ni * 16 + (l & 15)][kb];
            #pragma unroll
            for (int mi = 0; mi < 2; ++mi)
                #pragma unroll
                for (int ni = 0; ni < 2; ++ni)
                    acc[mi][ni] = __builtin_amdgcn_mfma_f32_16x16x32_bf16(
                        af[mi], bg[ni], acc[mi][ni], 0, 0, 0);
        }
        __syncthreads();
    }
    #pragma unroll
    for (int mi = 0; mi < 2; ++mi)
        #pragma unroll
        for (int ni = 0; ni < 2; ++ni) {
            int d = n0 + wn * 32 + ni * 16 + (l & 15);
            float bia = bias[d];
            #pragma unroll
            for (int r = 0; r < 4; ++r) {
                int b = b0 + wm * 32 + mi * 16 + (l >> 4) * 4 + r;
                float v = fmaxf(acc[mi][ni][r] + bia, 0.0f);
                fb[(size_t)b * D_F + d] = f2bf(v);
            }
        }
}

// ---------------- K7: big GEMM Z = Linv @ F^T, fused quad/out epilogue ----------
__global__ __launch_bounds__(512) void k_gmm(const unsigned short* __restrict__ linv,
                                             const unsigned short* __restrict__ fb,
                                             const float* __restrict__ cvec,
                                             const float* __restrict__ wmix,
                                             const float* __restrict__ ldet,
                                             float* __restrict__ out) {
    __shared__ unsigned short As[256][64];  // 32 KB
    __shared__ unsigned short Bs[128][64];  // 16 KB
    __shared__ float cb[D_F];
    __shared__ float qpart[4][128];
    int mk = blockIdx.x;
    int b0 = blockIdx.y * 128;
    int tid = threadIdx.x, w = tid >> 6, l = tid & 63;
    int wm = w >> 1, wn = w & 1;
    const unsigned short* Ab = linv + (size_t)mk * D_F * D_F;
    if (tid < D_F) cb[tid] = cvec[(size_t)mk * D_F + tid];
    f32x4 acc[4][4] = {};
    for (int k0 = 0; k0 < D_F; k0 += 64) {
        #pragma unroll
        for (int it = 0; it < 4; ++it) {
            int o16 = tid + it * 512;
            int r = o16 >> 3, c8 = o16 & 7;
            gload_lds16(Ab + (size_t)r * D_F + k0 + c8 * 8, &As[0][0] + o16 * 8);
        }
        #pragma unroll
        for (int it = 0; it < 2; ++it) {
            int o16 = tid + it * 512;
            int r = o16 >> 3, c8 = o16 & 7;
            gload_lds16(fb + (size_t)(b0 + r) * D_F + k0 + c8 * 8, &Bs[0][0] + o16 * 8);
        }
        __syncthreads();
        #pragma unroll
        for (int ks = 0; ks < 2; ++ks) {
            int kb = ks * 32 + (l >> 4) * 8;
            bf16x8 af[4], bg[4];
            #pragma unroll
            for (int mi = 0; mi < 4; ++mi)
                af[mi] = *(const bf16x8*)&As[wm * 64 + mi * 16 + (l & 15)][kb];
            #pragma unroll
            for (int ni = 0; ni < 4; ++ni)
                bg[ni] = *(const bf16x8*)&Bs[wn * 64 + ni * 16 + (l & 15)][kb];
            #pragma unroll
            for (int mi = 0; mi < 4; ++mi)
                #pragma unroll
                for (int ni = 0; ni < 4; ++ni)
                    acc[mi][ni] = __builtin_amdgcn_mfma_f32_16x16x32_bf16(
                        af[mi], bg[ni], acc[mi][ni], 0, 0, 0);
        }
        __syncthreads();
    }
    float p[4] = {0, 0, 0, 0};
    #pragma unroll
    for (int mi = 0; mi < 4; ++mi) {
        int ibase = wm * 64 + mi * 16 + ((l >> 4) << 2);
        #pragma unroll
        for (int r = 0; r < 4; ++r) {
            float cv = cb[ibase + r];
            #pragma unroll
            for (int ni = 0; ni < 4; ++ni) {
                float z = acc[mi][ni][r] - cv;
                p[ni] += z * z;
            }
        }
    }
    #pragma unroll
    for (int ni = 0; ni < 4; ++ni) {
        p[ni] += __shfl_xor(p[ni], 16);
        p[ni] += __shfl_xor(p[ni], 32);
    }
    if (l < 16) {
        #pragma unroll
        for (int ni = 0; ni < 4; ++ni)
            qpart[wm][wn * 64 + ni * 16 + l] = p[ni];
    }
    __syncthreads();
    if (tid < 128) {
        float q = qpart[0][tid] + qpart[1][tid] + qpart[2][tid] + qpart[3][tid];
        float lp = -0.5f * (q + (float)D_F * LOG2PI) - ldet[mk];
        out[(size_t)(b0 + tid) * MK + mk] = wmix[mk] * lp;
    }
}

extern "C" void kernel_launch(void* const* d_in, const int* in_sizes, int n_in,
                              void* d_out, int out_size, void* d_ws, size_t ws_size,
                              hipStream_t stream) {
    const float* x     = (const float*)d_in[0];
    const float* W     = (const float*)d_in[1];
    const float* bias  = (const float*)d_in[2];
    const float* means = (const float*)d_in[3];
    const float* covs  = (const float*)d_in[4];
    const float* wts   = (const float*)d_in[5];
    float* out = (float*)d_out;

    char* ws = (char*)d_ws;
    unsigned short* xb   = (unsigned short*)(ws);                    // 8 MB
    unsigned short* wt   = (unsigned short*)(ws + 8388608);          // 0.5 MB
    unsigned short* fb   = (unsigned short*)(ws + 8912896);          // 2 MB
    unsigned short* linv = (unsigned short*)(ws + 11010048);         // 10.5 MB
    float* cvec = (float*)(ws + 21495808);                           // 80 KB
    float* wmix = (float*)(ws + 21577728);                           // 320 B
    float* ldet = (float*)(ws + 21578048);                           // 320 B
    // dinv (2.62 MB bf16) aliases xb: xb is dead after k_feat, k_dinv runs after.
    unsigned short* dinv = (unsigned short*)(ws);

    k_cvt_x<<<dim3(2048), dim3(256), 0, stream>>>(x, xb);
    k_tw<<<dim3(16, 4), dim3(256), 0, stream>>>(W, wt);
    k_feat<<<dim3(64, 4), dim3(256), 0, stream>>>(xb, wt, bias, fb);   // last use of xb
    k_stats<<<dim3(MK), dim3(64), 0, stream>>>(covs, wts, wmix, ldet);
    k_dinv<<<dim3(MK, 4), dim3(64), 0, stream>>>(covs, dinv);          // writes into xb region
    k_inv_panel<<<dim3(MK, 4), dim3(256), 0, stream>>>(covs, dinv, linv);
    k_cvec<<<dim3(MK), dim3(256), 0, stream>>>(linv, means, cvec);
    k_gmm<<<dim3(MK, 32), dim3(512), 0, stream>>>(linv, fb, cvec, wmix, ldet, out);
}

// Round 3
// 123.724 us; speedup vs baseline: 4.9953x; 1.4309x over previous
//
#include <hip/hip_runtime.h>

#define B_N 4096
#define D_IN 1024
#define D_F 256
#define MK 80
#define LOG2PI 1.8378770664093453f
#define XP_S 72  // padded LDS row stride (bf16 elems) for inv_panel

typedef float f32x4 __attribute__((ext_vector_type(4)));
typedef short bf16x8 __attribute__((ext_vector_type(8)));
typedef float float4_ __attribute__((ext_vector_type(4)));
typedef unsigned int u32x4 __attribute__((ext_vector_type(4)));
typedef unsigned short u16x8 __attribute__((ext_vector_type(8)));

__device__ __forceinline__ unsigned short f2bf(float f) {
    unsigned u = __float_as_uint(f);
    u += 0x7fffu + ((u >> 16) & 1u);
    return (unsigned short)(u >> 16);
}
__device__ __forceinline__ float bf2f(unsigned short h) {
    return __uint_as_float(((unsigned)h) << 16);
}
__device__ __forceinline__ void gload_lds16(const void* g, void* l) {
    __builtin_amdgcn_global_load_lds((const __attribute__((address_space(1))) void*)g,
                                     (__attribute__((address_space(3))) void*)l, 16, 0, 0);
}
__device__ __forceinline__ bf16x8 pack8(float4_ a, float4_ b) {
    bf16x8 r;
    r[0] = (short)f2bf(a.x); r[1] = (short)f2bf(a.y);
    r[2] = (short)f2bf(a.z); r[3] = (short)f2bf(a.w);
    r[4] = (short)f2bf(b.x); r[5] = (short)f2bf(b.y);
    r[6] = (short)f2bf(b.z); r[7] = (short)f2bf(b.w);
    return r;
}

// ---------------- K_prep: fused x->bf16 cvt, W transpose, stats ----------------
// grid 1168: [0,64) = W-transpose tiles, [64,144) = per-component stats,
// [144,1168) = x conversion chunks.
__global__ __launch_bounds__(256) void k_prep(const float* __restrict__ x,
                                              const float* __restrict__ W,
                                              const float* __restrict__ covs,
                                              const float* __restrict__ wts,
                                              unsigned short* __restrict__ xb,
                                              unsigned short* __restrict__ wt,
                                              float* __restrict__ wmix,
                                              float* __restrict__ ldet) {
    int bx = blockIdx.x, tid = threadIdx.x;
    if (bx < 64) {
        __shared__ unsigned short t[64][65];
        int k0 = (bx >> 2) * 64, n0 = (bx & 3) * 64;
        int r = tid / 64, c = tid % 64;
        #pragma unroll
        for (int rr = r; rr < 64; rr += 4)
            t[rr][c] = f2bf(W[(size_t)(k0 + rr) * D_F + n0 + c]);
        __syncthreads();
        #pragma unroll
        for (int rr = r; rr < 64; rr += 4)
            wt[(size_t)(n0 + rr) * D_IN + k0 + c] = t[c][rr];
    } else if (bx < 144) {
        if (tid < 64) {
            int mk = bx - 64;
            int l = tid;
            const float* Lm = covs + (size_t)mk * D_F * D_F;
            float s = 0.0f;
            for (int i = l; i < D_F; i += 64) s += logf(Lm[(size_t)i * D_F + i]);
            for (int off = 32; off; off >>= 1) s += __shfl_down(s, off);
            if (l == 0) {
                ldet[mk] = s;
                int m = mk / 8, k = mk % 8;
                float mx = -1e30f;
                for (int j = 0; j < 8; j++) mx = fmaxf(mx, wts[m * 8 + j]);
                float sum = 0.0f;
                for (int j = 0; j < 8; j++) sum += expf(wts[m * 8 + j] - mx);
                wmix[mk] = expf(wts[m * 8 + k] - mx) / sum;
            }
        }
    } else {
        int idx = (bx - 144) * 256 + tid;
        int n4 = (B_N * D_IN) / 4;
        for (int i = idx; i < n4; i += 1024 * 256) {
            float4_ v = ((const float4_*)x)[i];
            ushort4 o;
            o.x = f2bf(v.x); o.y = f2bf(v.y); o.z = f2bf(v.z); o.w = f2bf(v.w);
            ((ushort4*)xb)[i] = o;
        }
    }
}

// ---------------- K5a: invert 64x64 diagonal blocks (fp32 solve, bf16 out) -----
__global__ __launch_bounds__(64) void k_dinv(const float* __restrict__ covs,
                                             unsigned short* __restrict__ dinv) {
    int mk = blockIdx.x, I = blockIdx.y;
    int i0 = I * 64;
    __shared__ float Ld[64 * 64];
    __shared__ float Xd[64][65];
    int l = threadIdx.x;
    const float* Cm = covs + (size_t)mk * D_F * D_F + (size_t)i0 * D_F + i0;
    for (int t = l; t < 1024; t += 64) {
        int r = t >> 4, s = t & 15;
        *(f32x4*)&Ld[r * 64 + s * 4] = *(const float4_*)&Cm[(size_t)r * D_F + s * 4];
    }
    __syncthreads();
    for (int i = 0; i < 64; ++i) {
        float s = 0.0f;
        for (int k = 0; k < i; ++k)
            s += Ld[i * 64 + k] * Xd[k][l];  // Ld read is wave-broadcast
        float v = (((i == l) ? 1.0f : 0.0f) - s) / Ld[i * 64 + i];
        Xd[i][l] = v;
    }
    unsigned short* D = dinv + ((size_t)mk * 4 + I) * 4096;
    for (int r = 0; r < 64; ++r)
        D[r * 64 + l] = f2bf(Xd[r][l]);  // coalesced
}

// ---------------- K5b: column panels of Linv via blocked MFMA + cvec partial ---
__global__ __launch_bounds__(256) void k_inv_panel(
        const float* __restrict__ covs,
        const unsigned short* __restrict__ dinv,
        const float* __restrict__ means,
        unsigned short* __restrict__ linv,
        float* __restrict__ cpart) {
    int mk = blockIdx.x, J = blockIdx.y;
    int jc0 = J * 64;
    __shared__ unsigned short Xp[4][64][XP_S];  // 73.7 KB
    __shared__ unsigned short Sb[64][XP_S];     // 9.2 KB
    __shared__ float muS[64];
    int tid = threadIdx.x, w = tid >> 6, l = tid & 63;
    const float* Cm = covs + (size_t)mk * D_F * D_F;
    unsigned short* Lout = linv + (size_t)mk * D_F * D_F;
    const unsigned short* Dmk = dinv + (size_t)mk * 4 * 4096;

    // 1) zero rows above the panel (upper triangle of these columns)
    for (int t = tid; t < jc0 * 8; t += 256) {
        int r = t >> 3, s = t & 7;
        ((u32x4*)(Lout + (size_t)r * D_F + jc0))[s] = (u32x4){0, 0, 0, 0};
    }
    // 2) Xp[J] = Dinv[J]^T + copy diag block rows to global
    const unsigned short* DJ = Dmk + J * 4096;
    for (int t = tid; t < 4096; t += 256) {
        int r = t >> 6, c = t & 63;
        Xp[J][c][r] = DJ[t];
    }
    for (int t = tid; t < 512; t += 256) {
        int r = t >> 3, s = t & 7;
        ((u32x4*)(Lout + (size_t)(jc0 + r) * D_F + jc0))[s] = ((const u32x4*)(DJ + r * 64))[s];
    }
    __syncthreads();

    for (int I = J + 1; I < 4; ++I) {
        // ---- GEMM-1: St = sum_K Xp[K] x L[I,K]^T ----
        f32x4 acc[4] = {};
        for (int K = J; K < I; ++K) {
            #pragma unroll
            for (int kb = 0; kb < 2; ++kb) {
                bf16x8 af = *(const bf16x8*)&Xp[K][w * 16 + (l & 15)][kb * 32 + (l >> 4) * 8];
                #pragma unroll
                for (int ni = 0; ni < 4; ++ni) {
                    const float* gp = Cm + (size_t)(I * 64 + ni * 16 + (l & 15)) * D_F
                                      + K * 64 + kb * 32 + (l >> 4) * 8;
                    bf16x8 bf = pack8(*(const float4_*)gp, *(const float4_*)(gp + 4));
                    acc[ni] = __builtin_amdgcn_mfma_f32_16x16x32_bf16(af, bf, acc[ni], 0, 0, 0);
                }
            }
        }
        #pragma unroll
        for (int ni = 0; ni < 4; ++ni)
            #pragma unroll
            for (int q = 0; q < 4; ++q)
                Sb[w * 16 + ((l >> 4) << 2) + q][ni * 16 + (l & 15)] = f2bf(acc[ni][q]);
        __syncthreads();
        // ---- GEMM-2: Xt[I] = St x (-Dinv[I])^T ----
        f32x4 acc2[4] = {};
        #pragma unroll
        for (int kb = 0; kb < 2; ++kb) {
            bf16x8 af = *(const bf16x8*)&Sb[w * 16 + (l & 15)][kb * 32 + (l >> 4) * 8];
            #pragma unroll
            for (int ni = 0; ni < 4; ++ni) {
                const u16x8* dp = (const u16x8*)(Dmk + (size_t)I * 4096
                                  + (ni * 16 + (l & 15)) * 64 + kb * 32 + (l >> 4) * 8);
                u16x8 dv = *dp ^ (unsigned short)0x8000;  // negate bf16
                bf16x8 bf = __builtin_bit_cast(bf16x8, dv);
                acc2[ni] = __builtin_amdgcn_mfma_f32_16x16x32_bf16(af, bf, acc2[ni], 0, 0, 0);
            }
        }
        #pragma unroll
        for (int ni = 0; ni < 4; ++ni)
            #pragma unroll
            for (int q = 0; q < 4; ++q) {
                int c = w * 16 + ((l >> 4) << 2) + q;
                int r = ni * 16 + (l & 15);
                unsigned short hv = f2bf(acc2[ni][q]);
                Xp[I][c][r] = hv;
                Lout[(size_t)(I * 64 + r) * D_F + jc0 + c] = hv;
            }
        __syncthreads();
    }

    // ---- cvec partial: cpart[mk][J][i] = sum_{c in panel} Linv[i][jc0+c]*mu[jc0+c]
    if (tid < 64) muS[tid] = means[(size_t)mk * D_F + jc0 + tid];
    __syncthreads();
    {
        int I = w, r = l;  // i = I*64 + r
        float s = 0.0f;
        if (I >= J) {
            for (int c = 0; c < 64; ++c)
                s += bf2f(Xp[I][c][r]) * muS[c];
        }
        cpart[((size_t)mk * 4 + J) * 256 + tid] = s;
    }
}

// ---------------- K4: extractor GEMM  F = relu(x @ W + b) -> bf16 [4096][256] ----
// LDS tiles use XOR-swizzled 16B-chunk layout (source-swizzled for global_load_lds).
__global__ __launch_bounds__(256) void k_feat(const unsigned short* __restrict__ xb,
                                              const unsigned short* __restrict__ wt,
                                              const float* __restrict__ bias,
                                              unsigned short* __restrict__ fb) {
    __shared__ unsigned short As[64][64];
    __shared__ unsigned short Bs[64][64];
    int b0 = blockIdx.x * 64;
    int n0 = blockIdx.y * 64;
    int tid = threadIdx.x, w = tid >> 6, l = tid & 63;
    int wm = w >> 1, wn = w & 1;
    f32x4 acc[2][2] = {};
    for (int k0 = 0; k0 < D_IN; k0 += 64) {
        #pragma unroll
        for (int it = 0; it < 2; ++it) {
            int o16 = tid + it * 256;
            int r = o16 >> 3, c8 = (o16 & 7) ^ (r & 7);
            gload_lds16(xb + (size_t)(b0 + r) * D_IN + k0 + c8 * 8, &As[0][0] + o16 * 8);
            gload_lds16(wt + (size_t)(n0 + r) * D_IN + k0 + c8 * 8, &Bs[0][0] + o16 * 8);
        }
        __syncthreads();
        #pragma unroll
        for (int ks = 0; ks < 2; ++ks) {
            int uw = ((ks * 4 + (l >> 4)) ^ (l & 7)) * 8;  // swizzled col (row%8 == l%8)
            bf16x8 af[2], bg[2];
            #pragma unroll
            for (int mi = 0; mi < 2; ++mi)
                af[mi] = *(const bf16x8*)&As[wm * 32 + mi * 16 + (l & 15)][uw];
            #pragma unroll
            for (int ni = 0; ni < 2; ++ni)
                bg[ni] = *(const bf16x8*)&Bs[wn * 32 + ni * 16 + (l & 15)][uw];
            #pragma unroll
            for (int mi = 0; mi < 2; ++mi)
                #pragma unroll
                for (int ni = 0; ni < 2; ++ni)
                    acc[mi][ni] = __builtin_amdgcn_mfma_f32_16x16x32_bf16(
                        af[mi], bg[ni], acc[mi][ni], 0, 0, 0);
        }
        __syncthreads();
    }
    #pragma unroll
    for (int mi = 0; mi < 2; ++mi)
        #pragma unroll
        for (int ni = 0; ni < 2; ++ni) {
            int d = n0 + wn * 32 + ni * 16 + (l & 15);
            float bia = bias[d];
            #pragma unroll
            for (int r = 0; r < 4; ++r) {
                int b = b0 + wm * 32 + mi * 16 + (l >> 4) * 4 + r;
                float v = fmaxf(acc[mi][ni][r] + bia, 0.0f);
                fb[(size_t)b * D_F + d] = f2bf(v);
            }
        }
}

// ---------------- K7: big GEMM Z = Linv @ F^T, fused quad/out epilogue ----------
__global__ __launch_bounds__(512) void k_gmm(const unsigned short* __restrict__ linv,
                                             const unsigned short* __restrict__ fb,
                                             const float* __restrict__ cpart,
                                             const float* __restrict__ wmix,
                                             const float* __restrict__ ldet,
                                             float* __restrict__ out) {
    __shared__ unsigned short As[256][64];  // 32 KB, swizzled 16B chunks
    __shared__ unsigned short Bs[128][64];  // 16 KB, swizzled
    __shared__ float cb[D_F];
    __shared__ float qpart[4][128];
    int mk = blockIdx.x;
    int b0 = blockIdx.y * 128;
    int tid = threadIdx.x, w = tid >> 6, l = tid & 63;
    int wm = w >> 1, wn = w & 1;
    const unsigned short* Ab = linv + (size_t)mk * D_F * D_F;
    if (tid < D_F) {
        const float* cp = cpart + (size_t)mk * 4 * D_F + tid;
        cb[tid] = cp[0] + cp[256] + cp[512] + cp[768];
    }
    f32x4 acc[4][4] = {};
    for (int k0 = 0; k0 < D_F; k0 += 64) {
        #pragma unroll
        for (int it = 0; it < 4; ++it) {
            int o16 = tid + it * 512;
            int r = o16 >> 3, c8 = (o16 & 7) ^ (r & 7);
            gload_lds16(Ab + (size_t)r * D_F + k0 + c8 * 8, &As[0][0] + o16 * 8);
        }
        #pragma unroll
        for (int it = 0; it < 2; ++it) {
            int o16 = tid + it * 512;
            int r = o16 >> 3, c8 = (o16 & 7) ^ (r & 7);
            gload_lds16(fb + (size_t)(b0 + r) * D_F + k0 + c8 * 8, &Bs[0][0] + o16 * 8);
        }
        __syncthreads();
        #pragma unroll
        for (int ks = 0; ks < 2; ++ks) {
            int uw = ((ks * 4 + (l >> 4)) ^ (l & 7)) * 8;  // swizzled col
            bf16x8 af[4], bg[4];
            #pragma unroll
            for (int mi = 0; mi < 4; ++mi)
                af[mi] = *(const bf16x8*)&As[wm * 64 + mi * 16 + (l & 15)][uw];
            #pragma unroll
            for (int ni = 0; ni < 4; ++ni)
                bg[ni] = *(const bf16x8*)&Bs[wn * 64 + ni * 16 + (l & 15)][uw];
            #pragma unroll
            for (int mi = 0; mi < 4; ++mi)
                #pragma unroll
                for (int ni = 0; ni < 4; ++ni)
                    acc[mi][ni] = __builtin_amdgcn_mfma_f32_16x16x32_bf16(
                        af[mi], bg[ni], acc[mi][ni], 0, 0, 0);
        }
        __syncthreads();
    }
    float p[4] = {0, 0, 0, 0};
    #pragma unroll
    for (int mi = 0; mi < 4; ++mi) {
        int ibase = wm * 64 + mi * 16 + ((l >> 4) << 2);
        #pragma unroll
        for (int r = 0; r < 4; ++r) {
            float cv = cb[ibase + r];
            #pragma unroll
            for (int ni = 0; ni < 4; ++ni) {
                float z = acc[mi][ni][r] - cv;
                p[ni] += z * z;
            }
        }
    }
    #pragma unroll
    for (int ni = 0; ni < 4; ++ni) {
        p[ni] += __shfl_xor(p[ni], 16);
        p[ni] += __shfl_xor(p[ni], 32);
    }
    if (l < 16) {
        #pragma unroll
        for (int ni = 0; ni < 4; ++ni)
            qpart[wm][wn * 64 + ni * 16 + l] = p[ni];
    }
    __syncthreads();
    if (tid < 128) {
        float q = qpart[0][tid] + qpart[1][tid] + qpart[2][tid] + qpart[3][tid];
        float lp = -0.5f * (q + (float)D_F * LOG2PI) - ldet[mk];
        out[(size_t)(b0 + tid) * MK + mk] = wmix[mk] * lp;
    }
}

extern "C" void kernel_launch(void* const* d_in, const int* in_sizes, int n_in,
                              void* d_out, int out_size, void* d_ws, size_t ws_size,
                              hipStream_t stream) {
    const float* x     = (const float*)d_in[0];
    const float* W     = (const float*)d_in[1];
    const float* bias  = (const float*)d_in[2];
    const float* means = (const float*)d_in[3];
    const float* covs  = (const float*)d_in[4];
    const float* wts   = (const float*)d_in[5];
    float* out = (float*)d_out;

    char* ws = (char*)d_ws;
    unsigned short* xb   = (unsigned short*)(ws);                    // 8 MB
    unsigned short* wt   = (unsigned short*)(ws + 8388608);          // 0.5 MB
    unsigned short* fb   = (unsigned short*)(ws + 8912896);          // 2 MB
    unsigned short* linv = (unsigned short*)(ws + 11010048);         // 10.5 MB
    float* wmix = (float*)(ws + 21577728);                           // 320 B
    float* ldet = (float*)(ws + 21578048);                           // 320 B
    // aliases: dinv (2.62 MB) -> xb region (xb dead after k_feat);
    //          cpart (320 KB) -> wt region (wt dead after k_feat).
    unsigned short* dinv = (unsigned short*)(ws);
    float* cpart = (float*)(ws + 8388608);

    k_prep<<<dim3(1168), dim3(256), 0, stream>>>(x, W, covs, wts, xb, wt, wmix, ldet);
    k_feat<<<dim3(64, 4), dim3(256), 0, stream>>>(xb, wt, bias, fb);   // last use of xb, wt
    k_dinv<<<dim3(MK, 4), dim3(64), 0, stream>>>(covs, dinv);          // writes xb region
    k_inv_panel<<<dim3(MK, 4), dim3(256), 0, stream>>>(covs, dinv, means, linv, cpart);
    k_gmm<<<dim3(MK, 32), dim3(512), 0, stream>>>(linv, fb, cpart, wmix, ldet, out);
}

// Round 4
// 112.455 us; speedup vs baseline: 5.4960x; 1.1002x over previous
//
#include <hip/hip_runtime.h>

#define B_N 4096
#define D_IN 1024
#define D_F 256
#define MK 80
#define LOG2PI 1.8378770664093453f
#define XP_S 72  // padded LDS row stride (bf16 elems) for inv_panel

typedef float f32x4 __attribute__((ext_vector_type(4)));
typedef short bf16x8 __attribute__((ext_vector_type(8)));
typedef float float4_ __attribute__((ext_vector_type(4)));
typedef unsigned int u32x4 __attribute__((ext_vector_type(4)));
typedef unsigned short u16x8 __attribute__((ext_vector_type(8)));

__device__ __forceinline__ unsigned short f2bf(float f) {
    unsigned u = __float_as_uint(f);
    u += 0x7fffu + ((u >> 16) & 1u);
    return (unsigned short)(u >> 16);
}
__device__ __forceinline__ float bf2f(unsigned short h) {
    return __uint_as_float(((unsigned)h) << 16);
}
__device__ __forceinline__ void gload_lds16(const void* g, void* l) {
    __builtin_amdgcn_global_load_lds((const __attribute__((address_space(1))) void*)g,
                                     (__attribute__((address_space(3))) void*)l, 16, 0, 0);
}
__device__ __forceinline__ bf16x8 pack8(float4_ a, float4_ b) {
    bf16x8 r;
    r[0] = (short)f2bf(a.x); r[1] = (short)f2bf(a.y);
    r[2] = (short)f2bf(a.z); r[3] = (short)f2bf(a.w);
    r[4] = (short)f2bf(b.x); r[5] = (short)f2bf(b.y);
    r[6] = (short)f2bf(b.z); r[7] = (short)f2bf(b.w);
    return r;
}

// ---------------- K_prep: fused W-transpose, stats, diag-block inversion -------
// grid 224: [0,64) W-transpose tiles, [64,144) stats, [144,224) dinv (wave = I).
__global__ __launch_bounds__(256) void k_prep(const float* __restrict__ W,
                                              const float* __restrict__ covs,
                                              const float* __restrict__ wts,
                                              unsigned short* __restrict__ wt,
                                              float* __restrict__ wmix,
                                              float* __restrict__ ldet,
                                              unsigned short* __restrict__ dinv) {
    int bx = blockIdx.x, tid = threadIdx.x;
    if (bx < 64) {
        __shared__ unsigned short t[64][65];
        int k0 = (bx >> 2) * 64, n0 = (bx & 3) * 64;
        int r = tid / 64, c = tid % 64;
        #pragma unroll
        for (int rr = r; rr < 64; rr += 4)
            t[rr][c] = f2bf(W[(size_t)(k0 + rr) * D_F + n0 + c]);
        __syncthreads();
        #pragma unroll
        for (int rr = r; rr < 64; rr += 4)
            wt[(size_t)(n0 + rr) * D_IN + k0 + c] = t[c][rr];
    } else if (bx < 144) {
        if (tid < 64) {
            int mk = bx - 64;
            int l = tid;
            const float* Lm = covs + (size_t)mk * D_F * D_F;
            float s = 0.0f;
            for (int i = l; i < D_F; i += 64) s += logf(Lm[(size_t)i * D_F + i]);
            for (int off = 32; off; off >>= 1) s += __shfl_down(s, off);
            if (l == 0) {
                ldet[mk] = s;
                int m = mk / 8, k = mk % 8;
                float mx = -1e30f;
                for (int j = 0; j < 8; j++) mx = fmaxf(mx, wts[m * 8 + j]);
                float sum = 0.0f;
                for (int j = 0; j < 8; j++) sum += expf(wts[m * 8 + j] - mx);
                wmix[mk] = expf(wts[m * 8 + k] - mx) / sum;
            }
        }
    } else {
        // dinv: wave w inverts 64x64 diag block I=w of component mk.
        // Lane l owns column l: x[k] (k-th row entry of column l) is LANE-LOCAL.
        int mk = bx - 144;
        int w = tid >> 6, l = tid & 63;
        const float* Lb = covs + (size_t)mk * D_F * D_F + (size_t)(w * 64) * D_F + w * 64;
        float xc[64];
        #pragma unroll
        for (int i = 0; i < 64; ++i) {
            const float* Lr = Lb + (size_t)i * D_F;
            float s0 = 0.f, s1 = 0.f, s2 = 0.f, s3 = 0.f;
            #pragma unroll
            for (int k = 0; k + 3 < i; k += 4) {
                s0 += Lr[k] * xc[k];
                s1 += Lr[k + 1] * xc[k + 1];
                s2 += Lr[k + 2] * xc[k + 2];
                s3 += Lr[k + 3] * xc[k + 3];
            }
            #pragma unroll
            for (int k = i & ~3; k < i; ++k) s0 += Lr[k] * xc[k];
            float v = (((i == l) ? 1.0f : 0.0f) - ((s0 + s1) + (s2 + s3))) / Lr[i];
            xc[i] = v;
        }
        unsigned short* D = dinv + ((size_t)mk * 4 + w) * 4096;
        #pragma unroll
        for (int r = 0; r < 64; ++r)
            D[r * 64 + l] = f2bf(xc[r]);  // coalesced 128B rows
    }
}

// ---------------- K5b: column panels of Linv via blocked MFMA + cvec partial ---
__global__ __launch_bounds__(256) void k_inv_panel(
        const float* __restrict__ covs,
        const unsigned short* __restrict__ dinv,
        const float* __restrict__ means,
        unsigned short* __restrict__ linv,
        float* __restrict__ cpart) {
    int mk = blockIdx.x, J = blockIdx.y;
    int jc0 = J * 64;
    __shared__ unsigned short Xp[4][64][XP_S];  // 73.7 KB
    __shared__ unsigned short Sb[64][XP_S];     // 9.2 KB
    __shared__ float muS[64];
    int tid = threadIdx.x, w = tid >> 6, l = tid & 63;
    const float* Cm = covs + (size_t)mk * D_F * D_F;
    unsigned short* Lout = linv + (size_t)mk * D_F * D_F;
    const unsigned short* Dmk = dinv + (size_t)mk * 4 * 4096;

    for (int t = tid; t < jc0 * 8; t += 256) {
        int r = t >> 3, s = t & 7;
        ((u32x4*)(Lout + (size_t)r * D_F + jc0))[s] = (u32x4){0, 0, 0, 0};
    }
    const unsigned short* DJ = Dmk + J * 4096;
    for (int t = tid; t < 4096; t += 256) {
        int r = t >> 6, c = t & 63;
        Xp[J][c][r] = DJ[t];
    }
    for (int t = tid; t < 512; t += 256) {
        int r = t >> 3, s = t & 7;
        ((u32x4*)(Lout + (size_t)(jc0 + r) * D_F + jc0))[s] = ((const u32x4*)(DJ + r * 64))[s];
    }
    __syncthreads();

    for (int I = J + 1; I < 4; ++I) {
        f32x4 acc[4] = {};
        for (int K = J; K < I; ++K) {
            #pragma unroll
            for (int kb = 0; kb < 2; ++kb) {
                bf16x8 af = *(const bf16x8*)&Xp[K][w * 16 + (l & 15)][kb * 32 + (l >> 4) * 8];
                #pragma unroll
                for (int ni = 0; ni < 4; ++ni) {
                    const float* gp = Cm + (size_t)(I * 64 + ni * 16 + (l & 15)) * D_F
                                      + K * 64 + kb * 32 + (l >> 4) * 8;
                    bf16x8 bf = pack8(*(const float4_*)gp, *(const float4_*)(gp + 4));
                    acc[ni] = __builtin_amdgcn_mfma_f32_16x16x32_bf16(af, bf, acc[ni], 0, 0, 0);
                }
            }
        }
        #pragma unroll
        for (int ni = 0; ni < 4; ++ni)
            #pragma unroll
            for (int q = 0; q < 4; ++q)
                Sb[w * 16 + ((l >> 4) << 2) + q][ni * 16 + (l & 15)] = f2bf(acc[ni][q]);
        __syncthreads();
        f32x4 acc2[4] = {};
        #pragma unroll
        for (int kb = 0; kb < 2; ++kb) {
            bf16x8 af = *(const bf16x8*)&Sb[w * 16 + (l & 15)][kb * 32 + (l >> 4) * 8];
            #pragma unroll
            for (int ni = 0; ni < 4; ++ni) {
                const u16x8* dp = (const u16x8*)(Dmk + (size_t)I * 4096
                                  + (ni * 16 + (l & 15)) * 64 + kb * 32 + (l >> 4) * 8);
                u16x8 dv = *dp ^ (unsigned short)0x8000;  // negate bf16
                bf16x8 bf = __builtin_bit_cast(bf16x8, dv);
                acc2[ni] = __builtin_amdgcn_mfma_f32_16x16x32_bf16(af, bf, acc2[ni], 0, 0, 0);
            }
        }
        #pragma unroll
        for (int ni = 0; ni < 4; ++ni)
            #pragma unroll
            for (int q = 0; q < 4; ++q) {
                int c = w * 16 + ((l >> 4) << 2) + q;
                int r = ni * 16 + (l & 15);
                unsigned short hv = f2bf(acc2[ni][q]);
                Xp[I][c][r] = hv;
                Lout[(size_t)(I * 64 + r) * D_F + jc0 + c] = hv;
            }
        __syncthreads();
    }

    if (tid < 64) muS[tid] = means[(size_t)mk * D_F + jc0 + tid];
    __syncthreads();
    {
        int I = w, r = l;
        float s = 0.0f;
        if (I >= J) {
            for (int c = 0; c < 64; ++c)
                s += bf2f(Xp[I][c][r]) * muS[c];
        }
        cpart[((size_t)mk * 4 + J) * 256 + tid] = s;
    }
}

// ---------------- K4: extractor GEMM  F = relu(x @ W + b), x read as f32 -------
__global__ __launch_bounds__(256) void k_feat(const float* __restrict__ x,
                                              const unsigned short* __restrict__ wt,
                                              const float* __restrict__ bias,
                                              unsigned short* __restrict__ fb) {
    __shared__ unsigned short As[64][64];
    __shared__ unsigned short Bs[64][64];
    int b0 = blockIdx.x * 64;
    int n0 = blockIdx.y * 64;
    int tid = threadIdx.x, w = tid >> 6, l = tid & 63;
    int wm = w >> 1, wn = w & 1;
    f32x4 acc[2][2] = {};
    for (int k0 = 0; k0 < D_IN; k0 += 64) {
        // A: load f32 x to regs (issues before barrier), convert, swizzled ds_write
        float4_ av[2][2];
        #pragma unroll
        for (int it = 0; it < 2; ++it) {
            int o16 = tid + it * 256;
            int r = o16 >> 3, c = o16 & 7;
            const float* gp = x + (size_t)(b0 + r) * D_IN + k0 + c * 8;
            av[it][0] = *(const float4_*)gp;
            av[it][1] = *(const float4_*)(gp + 4);
        }
        __syncthreads();  // previous compute done reading LDS
        #pragma unroll
        for (int it = 0; it < 2; ++it) {
            int o16 = tid + it * 256;
            int r = o16 >> 3, c = o16 & 7;
            int cs = c ^ (r & 7);
            *(bf16x8*)&As[r][cs * 8] = pack8(av[it][0], av[it][1]);
            int c8 = c ^ (r & 7);
            gload_lds16(wt + (size_t)(n0 + r) * D_IN + k0 + c8 * 8, &Bs[0][0] + o16 * 8);
        }
        __syncthreads();  // staging complete (vmcnt+lgkm drained)
        #pragma unroll
        for (int ks = 0; ks < 2; ++ks) {
            int uw = ((ks * 4 + (l >> 4)) ^ (l & 7)) * 8;  // swizzled col
            bf16x8 af[2], bg[2];
            #pragma unroll
            for (int mi = 0; mi < 2; ++mi)
                af[mi] = *(const bf16x8*)&As[wm * 32 + mi * 16 + (l & 15)][uw];
            #pragma unroll
            for (int ni = 0; ni < 2; ++ni)
                bg[ni] = *(const bf16x8*)&Bs[wn * 32 + ni * 16 + (l & 15)][uw];
            #pragma unroll
            for (int mi = 0; mi < 2; ++mi)
                #pragma unroll
                for (int ni = 0; ni < 2; ++ni)
                    acc[mi][ni] = __builtin_amdgcn_mfma_f32_16x16x32_bf16(
                        af[mi], bg[ni], acc[mi][ni], 0, 0, 0);
        }
    }
    #pragma unroll
    for (int mi = 0; mi < 2; ++mi)
        #pragma unroll
        for (int ni = 0; ni < 2; ++ni) {
            int d = n0 + wn * 32 + ni * 16 + (l & 15);
            float bia = bias[d];
            #pragma unroll
            for (int r = 0; r < 4; ++r) {
                int b = b0 + wm * 32 + mi * 16 + (l >> 4) * 4 + r;
                float v = fmaxf(acc[mi][ni][r] + bia, 0.0f);
                fb[(size_t)b * D_F + d] = f2bf(v);
            }
        }
}

// ---------------- K7: big GEMM Z = Linv @ F^T, 256x256 tile, dbuf prefetch -----
// 8 waves (2M x 4N), wave tile 128x64, BK=64, LDS double-buffered (2 x 64 KB).
__global__ __launch_bounds__(512) void k_gmm(const unsigned short* __restrict__ linv,
                                             const unsigned short* __restrict__ fb,
                                             const float* __restrict__ cpart,
                                             const float* __restrict__ wmix,
                                             const float* __restrict__ ldet,
                                             float* __restrict__ out) {
    __shared__ unsigned short AB[2][32768];  // [buf][A 256x64 | B 256x64] = 128 KB
    __shared__ float cb[D_F];
    __shared__ float qpart[2][256];
    int b0 = blockIdx.x * 256;
    int mk = blockIdx.y;
    int tid = threadIdx.x, w = tid >> 6, l = tid & 63;
    int wm = w >> 2, wn = w & 3;
    const unsigned short* Ab = linv + (size_t)mk * D_F * D_F;
    if (tid < D_F) {
        const float* cp = cpart + (size_t)mk * 4 * D_F + tid;
        cb[tid] = cp[0] + cp[256] + cp[512] + cp[768];
    }
    f32x4 acc[8][4] = {};

    auto STAGE = [&](int buf, int t) {
        int k0 = t * 64;
        unsigned short* base = &AB[buf][0];
        #pragma unroll
        for (int it = 0; it < 4; ++it) {
            int o = tid + it * 512;
            int r = o >> 3, c8 = (o & 7) ^ (r & 7);
            gload_lds16(Ab + (size_t)r * D_F + k0 + c8 * 8, base + o * 8);
        }
        #pragma unroll
        for (int it = 0; it < 4; ++it) {
            int o = tid + it * 512;
            int r = o >> 3, c8 = (o & 7) ^ (r & 7);
            gload_lds16(fb + (size_t)(b0 + r) * D_F + k0 + c8 * 8, base + 16384 + o * 8);
        }
    };

    STAGE(0, 0);
    __syncthreads();  // buf0 staged (drains vmcnt)
    int cur = 0;
    for (int t = 0; t < 4; ++t) {
        if (t < 3) STAGE(cur ^ 1, t + 1);  // prefetch in flight during MFMA
        const unsigned short(*As)[64] = (const unsigned short(*)[64]) & AB[cur][0];
        const unsigned short(*Bs)[64] = (const unsigned short(*)[64]) & AB[cur][16384];
        __builtin_amdgcn_s_setprio(1);
        #pragma unroll
        for (int ks = 0; ks < 2; ++ks) {
            int uw = ((ks * 4 + (l >> 4)) ^ (l & 7)) * 8;
            bf16x8 bg[4];
            #pragma unroll
            for (int ni = 0; ni < 4; ++ni)
                bg[ni] = *(const bf16x8*)&Bs[wn * 64 + ni * 16 + (l & 15)][uw];
            #pragma unroll
            for (int mi = 0; mi < 8; ++mi) {
                bf16x8 af = *(const bf16x8*)&As[wm * 128 + mi * 16 + (l & 15)][uw];
                #pragma unroll
                for (int ni = 0; ni < 4; ++ni)
                    acc[mi][ni] = __builtin_amdgcn_mfma_f32_16x16x32_bf16(
                        af, bg[ni], acc[mi][ni], 0, 0, 0);
            }
        }
        __builtin_amdgcn_s_setprio(0);
        __syncthreads();  // drains prefetch (hidden under MFMA) + read-release
        cur ^= 1;
    }

    float p[4] = {0, 0, 0, 0};
    #pragma unroll
    for (int mi = 0; mi < 8; ++mi) {
        int ibase = wm * 128 + mi * 16 + ((l >> 4) << 2);
        #pragma unroll
        for (int r = 0; r < 4; ++r) {
            float cv = cb[ibase + r];
            #pragma unroll
            for (int ni = 0; ni < 4; ++ni) {
                float z = acc[mi][ni][r] - cv;
                p[ni] += z * z;
            }
        }
    }
    #pragma unroll
    for (int ni = 0; ni < 4; ++ni) {
        p[ni] += __shfl_xor(p[ni], 16);
        p[ni] += __shfl_xor(p[ni], 32);
    }
    if (l < 16) {
        #pragma unroll
        for (int ni = 0; ni < 4; ++ni)
            qpart[wm][wn * 64 + ni * 16 + l] = p[ni];
    }
    __syncthreads();
    if (tid < 256) {
        float q = qpart[0][tid] + qpart[1][tid];
        float lp = -0.5f * (q + (float)D_F * LOG2PI) - ldet[mk];
        out[(size_t)(b0 + tid) * MK + mk] = wmix[mk] * lp;
    }
}

extern "C" void kernel_launch(void* const* d_in, const int* in_sizes, int n_in,
                              void* d_out, int out_size, void* d_ws, size_t ws_size,
                              hipStream_t stream) {
    const float* x     = (const float*)d_in[0];
    const float* W     = (const float*)d_in[1];
    const float* bias  = (const float*)d_in[2];
    const float* means = (const float*)d_in[3];
    const float* covs  = (const float*)d_in[4];
    const float* wts   = (const float*)d_in[5];
    float* out = (float*)d_out;

    char* ws = (char*)d_ws;
    unsigned short* dinv = (unsigned short*)(ws);                    // 2.62 MB
    unsigned short* wt   = (unsigned short*)(ws + 8388608);          // 0.5 MB (k_feat B)
    unsigned short* fb   = (unsigned short*)(ws + 8912896);          // 2 MB
    unsigned short* linv = (unsigned short*)(ws + 11010048);         // 10.5 MB
    float* wmix = (float*)(ws + 21577728);                           // 320 B
    float* ldet = (float*)(ws + 21578048);                           // 320 B
    // cpart (320 KB) aliases wt region: wt is dead after k_feat, cpart written after.
    float* cpart = (float*)(ws + 8388608);

    k_prep<<<dim3(224), dim3(256), 0, stream>>>(W, covs, wts, wt, wmix, ldet, dinv);
    k_feat<<<dim3(64, 4), dim3(256), 0, stream>>>(x, wt, bias, fb);     // last use of wt
    k_inv_panel<<<dim3(MK, 4), dim3(256), 0, stream>>>(covs, dinv, means, linv, cpart);
    k_gmm<<<dim3(16, MK), dim3(512), 0, stream>>>(linv, fb, cpart, wmix, ldet, out);
}

// Round 5
// 103.270 us; speedup vs baseline: 5.9847x; 1.0889x over previous
//
#include <hip/hip_runtime.h>

#define B_N 4096
#define D_IN 1024
#define D_F 256
#define MK 80
#define LOG2PI 1.8378770664093453f
#define XP_S 72  // padded LDS row stride (bf16 elems) for inv_panel

typedef float f32x4 __attribute__((ext_vector_type(4)));
typedef short bf16x8 __attribute__((ext_vector_type(8)));
typedef float float4_ __attribute__((ext_vector_type(4)));
typedef unsigned int u32x4 __attribute__((ext_vector_type(4)));
typedef unsigned short u16x8 __attribute__((ext_vector_type(8)));

__device__ __forceinline__ unsigned short f2bf(float f) {
    unsigned u = __float_as_uint(f);
    u += 0x7fffu + ((u >> 16) & 1u);
    return (unsigned short)(u >> 16);
}
__device__ __forceinline__ float bf2f(unsigned short h) {
    return __uint_as_float(((unsigned)h) << 16);
}
__device__ __forceinline__ void gload_lds16(const void* g, void* l) {
    __builtin_amdgcn_global_load_lds((const __attribute__((address_space(1))) void*)g,
                                     (__attribute__((address_space(3))) void*)l, 16, 0, 0);
}
__device__ __forceinline__ bf16x8 pack8(float4_ a, float4_ b) {
    bf16x8 r;
    r[0] = (short)f2bf(a.x); r[1] = (short)f2bf(a.y);
    r[2] = (short)f2bf(a.z); r[3] = (short)f2bf(a.w);
    r[4] = (short)f2bf(b.x); r[5] = (short)f2bf(b.y);
    r[6] = (short)f2bf(b.z); r[7] = (short)f2bf(b.w);
    return r;
}

// ---------------- K_pre: W-transpose, stats, diag-block inversion, covs->bf16 --
// grid 304: [0,64) W-transpose tiles, [64,144) stats, [144,224) dinv (wave = I),
// [224,304) covs off-diag block f32->bf16 conversion.
__global__ __launch_bounds__(256) void k_pre(const float* __restrict__ W,
                                             const float* __restrict__ covs,
                                             const float* __restrict__ wts,
                                             unsigned short* __restrict__ wt,
                                             float* __restrict__ wmix,
                                             float* __restrict__ ldet,
                                             unsigned short* __restrict__ dinv,
                                             unsigned short* __restrict__ covsb) {
    int bx = blockIdx.x, tid = threadIdx.x;
    if (bx < 64) {
        __shared__ unsigned short t[64][65];
        int k0 = (bx >> 2) * 64, n0 = (bx & 3) * 64;
        int r = tid / 64, c = tid % 64;
        #pragma unroll
        for (int rr = r; rr < 64; rr += 4)
            t[rr][c] = f2bf(W[(size_t)(k0 + rr) * D_F + n0 + c]);
        __syncthreads();
        #pragma unroll
        for (int rr = r; rr < 64; rr += 4)
            wt[(size_t)(n0 + rr) * D_IN + k0 + c] = t[c][rr];
    } else if (bx < 144) {
        if (tid < 64) {
            int mk = bx - 64;
            int l = tid;
            const float* Lm = covs + (size_t)mk * D_F * D_F;
            float s = 0.0f;
            for (int i = l; i < D_F; i += 64) s += logf(Lm[(size_t)i * D_F + i]);
            for (int off = 32; off; off >>= 1) s += __shfl_down(s, off);
            if (l == 0) {
                ldet[mk] = s;
                int m = mk / 8, k = mk % 8;
                float mx = -1e30f;
                for (int j = 0; j < 8; j++) mx = fmaxf(mx, wts[m * 8 + j]);
                float sum = 0.0f;
                for (int j = 0; j < 8; j++) sum += expf(wts[m * 8 + j] - mx);
                wmix[mk] = expf(wts[m * 8 + k] - mx) / sum;
            }
        }
    } else if (bx < 224) {
        // dinv: wave w inverts 64x64 diag block I=w of component mk.
        int mk = bx - 144;
        int w = tid >> 6, l = tid & 63;
        const float* Lb = covs + (size_t)mk * D_F * D_F + (size_t)(w * 64) * D_F + w * 64;
        float xc[64];
        #pragma unroll
        for (int i = 0; i < 64; ++i) {
            const float* Lr = Lb + (size_t)i * D_F;
            float s0 = 0.f, s1 = 0.f, s2 = 0.f, s3 = 0.f;
            #pragma unroll
            for (int k = 0; k + 3 < i; k += 4) {
                s0 += Lr[k] * xc[k];
                s1 += Lr[k + 1] * xc[k + 1];
                s2 += Lr[k + 2] * xc[k + 2];
                s3 += Lr[k + 3] * xc[k + 3];
            }
            #pragma unroll
            for (int k = i & ~3; k < i; ++k) s0 += Lr[k] * xc[k];
            float v = (((i == l) ? 1.0f : 0.0f) - ((s0 + s1) + (s2 + s3))) / Lr[i];
            xc[i] = v;
        }
        unsigned short* D = dinv + ((size_t)mk * 4 + w) * 4096;
        #pragma unroll
        for (int r = 0; r < 64; ++r)
            D[r * 64 + l] = f2bf(xc[r]);  // coalesced 128B rows
    } else {
        // covs off-diag lower blocks -> bf16: (I,K), K<I, idx = I*(I-1)/2+K
        int mk = bx - 224;
        const float* Cm = covs + (size_t)mk * D_F * D_F;
        unsigned short* Cb = covsb + (size_t)mk * 6 * 4096;
        #pragma unroll
        for (int I = 1; I < 4; ++I)
            for (int K = 0; K < I; ++K) {
                int idx = (I * (I - 1)) / 2 + K;
                for (int t = tid; t < 4096; t += 256) {
                    int r = t >> 6, k = t & 63;
                    Cb[(size_t)idx * 4096 + t] =
                        f2bf(Cm[(size_t)(I * 64 + r) * D_F + K * 64 + k]);
                }
            }
    }
}

// ---------------- K5b: column panels of Linv via blocked MFMA + cvec partial ---
__global__ __launch_bounds__(256) void k_inv_panel(
        const unsigned short* __restrict__ covsb,
        const unsigned short* __restrict__ dinv,
        const float* __restrict__ means,
        unsigned short* __restrict__ linv,
        float* __restrict__ cpart) {
    int mk = blockIdx.x, J = blockIdx.y;
    int jc0 = J * 64;
    __shared__ unsigned short Xp[4][64][XP_S];  // 73.7 KB
    __shared__ unsigned short Sb[64][XP_S];     // 9.2 KB
    __shared__ float muS[64];
    int tid = threadIdx.x, w = tid >> 6, l = tid & 63;
    const unsigned short* Cb = covsb + (size_t)mk * 6 * 4096;
    unsigned short* Lout = linv + (size_t)mk * D_F * D_F;
    const unsigned short* Dmk = dinv + (size_t)mk * 4 * 4096;

    for (int t = tid; t < jc0 * 8; t += 256) {
        int r = t >> 3, s = t & 7;
        ((u32x4*)(Lout + (size_t)r * D_F + jc0))[s] = (u32x4){0, 0, 0, 0};
    }
    const unsigned short* DJ = Dmk + J * 4096;
    for (int t = tid; t < 4096; t += 256) {
        int r = t >> 6, c = t & 63;
        Xp[J][c][r] = DJ[t];
    }
    for (int t = tid; t < 512; t += 256) {
        int r = t >> 3, s = t & 7;
        ((u32x4*)(Lout + (size_t)(jc0 + r) * D_F + jc0))[s] = ((const u32x4*)(DJ + r * 64))[s];
    }
    __syncthreads();

    for (int I = J + 1; I < 4; ++I) {
        f32x4 acc[4] = {};
        for (int K = J; K < I; ++K) {
            const unsigned short* CB = Cb + (size_t)((I * (I - 1)) / 2 + K) * 4096;
            #pragma unroll
            for (int kb = 0; kb < 2; ++kb) {
                bf16x8 af = *(const bf16x8*)&Xp[K][w * 16 + (l & 15)][kb * 32 + (l >> 4) * 8];
                #pragma unroll
                for (int ni = 0; ni < 4; ++ni) {
                    bf16x8 bf = *(const bf16x8*)&CB[(size_t)(ni * 16 + (l & 15)) * 64
                                                    + kb * 32 + (l >> 4) * 8];
                    acc[ni] = __builtin_amdgcn_mfma_f32_16x16x32_bf16(af, bf, acc[ni], 0, 0, 0);
                }
            }
        }
        #pragma unroll
        for (int ni = 0; ni < 4; ++ni)
            #pragma unroll
            for (int q = 0; q < 4; ++q)
                Sb[w * 16 + ((l >> 4) << 2) + q][ni * 16 + (l & 15)] = f2bf(acc[ni][q]);
        __syncthreads();
        f32x4 acc2[4] = {};
        #pragma unroll
        for (int kb = 0; kb < 2; ++kb) {
            bf16x8 af = *(const bf16x8*)&Sb[w * 16 + (l & 15)][kb * 32 + (l >> 4) * 8];
            #pragma unroll
            for (int ni = 0; ni < 4; ++ni) {
                const u16x8* dp = (const u16x8*)(Dmk + (size_t)I * 4096
                                  + (ni * 16 + (l & 15)) * 64 + kb * 32 + (l >> 4) * 8);
                u16x8 dv = *dp ^ (unsigned short)0x8000;  // negate bf16
                bf16x8 bf = __builtin_bit_cast(bf16x8, dv);
                acc2[ni] = __builtin_amdgcn_mfma_f32_16x16x32_bf16(af, bf, acc2[ni], 0, 0, 0);
            }
        }
        #pragma unroll
        for (int ni = 0; ni < 4; ++ni)
            #pragma unroll
            for (int q = 0; q < 4; ++q) {
                int c = w * 16 + ((l >> 4) << 2) + q;
                int r = ni * 16 + (l & 15);
                unsigned short hv = f2bf(acc2[ni][q]);
                Xp[I][c][r] = hv;
                Lout[(size_t)(I * 64 + r) * D_F + jc0 + c] = hv;
            }
        __syncthreads();
    }

    if (tid < 64) muS[tid] = means[(size_t)mk * D_F + jc0 + tid];
    __syncthreads();
    {
        int I = w, r = l;
        float s = 0.0f;
        if (I >= J) {
            for (int c = 0; c < 64; ++c)
                s += bf2f(Xp[I][c][r]) * muS[c];
        }
        cpart[((size_t)mk * 4 + J) * 256 + tid] = s;
    }
}

// ---------------- K4: extractor GEMM  F = relu(x @ W + b), x read as f32 -------
__global__ __launch_bounds__(256) void k_feat(const float* __restrict__ x,
                                              const unsigned short* __restrict__ wt,
                                              const float* __restrict__ bias,
                                              unsigned short* __restrict__ fb) {
    __shared__ unsigned short As[64][64];
    __shared__ unsigned short Bs[64][64];
    int b0 = blockIdx.x * 64;
    int n0 = blockIdx.y * 64;
    int tid = threadIdx.x, w = tid >> 6, l = tid & 63;
    int wm = w >> 1, wn = w & 1;
    f32x4 acc[2][2] = {};
    for (int k0 = 0; k0 < D_IN; k0 += 64) {
        float4_ av[2][2];
        #pragma unroll
        for (int it = 0; it < 2; ++it) {
            int o16 = tid + it * 256;
            int r = o16 >> 3, c = o16 & 7;
            const float* gp = x + (size_t)(b0 + r) * D_IN + k0 + c * 8;
            av[it][0] = *(const float4_*)gp;
            av[it][1] = *(const float4_*)(gp + 4);
        }
        __syncthreads();  // previous compute done reading LDS
        #pragma unroll
        for (int it = 0; it < 2; ++it) {
            int o16 = tid + it * 256;
            int r = o16 >> 3, c = o16 & 7;
            int cs = c ^ (r & 7);
            *(bf16x8*)&As[r][cs * 8] = pack8(av[it][0], av[it][1]);
            int c8 = c ^ (r & 7);
            gload_lds16(wt + (size_t)(n0 + r) * D_IN + k0 + c8 * 8, &Bs[0][0] + o16 * 8);
        }
        __syncthreads();  // staging complete
        #pragma unroll
        for (int ks = 0; ks < 2; ++ks) {
            int uw = ((ks * 4 + (l >> 4)) ^ (l & 7)) * 8;  // swizzled col
            bf16x8 af[2], bg[2];
            #pragma unroll
            for (int mi = 0; mi < 2; ++mi)
                af[mi] = *(const bf16x8*)&As[wm * 32 + mi * 16 + (l & 15)][uw];
            #pragma unroll
            for (int ni = 0; ni < 2; ++ni)
                bg[ni] = *(const bf16x8*)&Bs[wn * 32 + ni * 16 + (l & 15)][uw];
            #pragma unroll
            for (int mi = 0; mi < 2; ++mi)
                #pragma unroll
                for (int ni = 0; ni < 2; ++ni)
                    acc[mi][ni] = __builtin_amdgcn_mfma_f32_16x16x32_bf16(
                        af[mi], bg[ni], acc[mi][ni], 0, 0, 0);
        }
    }
    #pragma unroll
    for (int mi = 0; mi < 2; ++mi)
        #pragma unroll
        for (int ni = 0; ni < 2; ++ni) {
            int d = n0 + wn * 32 + ni * 16 + (l & 15);
            float bia = bias[d];
            #pragma unroll
            for (int r = 0; r < 4; ++r) {
                int b = b0 + wm * 32 + mi * 16 + (l >> 4) * 4 + r;
                float v = fmaxf(acc[mi][ni][r] + bia, 0.0f);
                fb[(size_t)b * D_F + d] = f2bf(v);
            }
        }
}

// ---------------- K7: big GEMM Z = Linv @ F^T (R3-proven structure) ------------
// BM=256 (all i of one component), BN=128 (batch), BK=64. 512 threads = 8 waves.
__global__ __launch_bounds__(512) void k_gmm(const unsigned short* __restrict__ linv,
                                             const unsigned short* __restrict__ fb,
                                             const float* __restrict__ cpart,
                                             const float* __restrict__ wmix,
                                             const float* __restrict__ ldet,
                                             float* __restrict__ out) {
    __shared__ unsigned short As[256][64];  // 32 KB, swizzled 16B chunks
    __shared__ unsigned short Bs[128][64];  // 16 KB, swizzled
    __shared__ float cb[D_F];
    __shared__ float qpart[4][128];
    int mk = blockIdx.x;
    int b0 = blockIdx.y * 128;
    int tid = threadIdx.x, w = tid >> 6, l = tid & 63;
    int wm = w >> 1, wn = w & 1;
    const unsigned short* Ab = linv + (size_t)mk * D_F * D_F;
    if (tid < D_F) {
        const float* cp = cpart + (size_t)mk * 4 * D_F + tid;
        cb[tid] = cp[0] + cp[256] + cp[512] + cp[768];
    }
    f32x4 acc[4][4] = {};
    for (int k0 = 0; k0 < D_F; k0 += 64) {
        #pragma unroll
        for (int it = 0; it < 4; ++it) {
            int o16 = tid + it * 512;
            int r = o16 >> 3, c8 = (o16 & 7) ^ (r & 7);
            gload_lds16(Ab + (size_t)r * D_F + k0 + c8 * 8, &As[0][0] + o16 * 8);
        }
        #pragma unroll
        for (int it = 0; it < 2; ++it) {
            int o16 = tid + it * 512;
            int r = o16 >> 3, c8 = (o16 & 7) ^ (r & 7);
            gload_lds16(fb + (size_t)(b0 + r) * D_F + k0 + c8 * 8, &Bs[0][0] + o16 * 8);
        }
        __syncthreads();
        #pragma unroll
        for (int ks = 0; ks < 2; ++ks) {
            int uw = ((ks * 4 + (l >> 4)) ^ (l & 7)) * 8;  // swizzled col
            bf16x8 af[4], bg[4];
            #pragma unroll
            for (int mi = 0; mi < 4; ++mi)
                af[mi] = *(const bf16x8*)&As[wm * 64 + mi * 16 + (l & 15)][uw];
            #pragma unroll
            for (int ni = 0; ni < 4; ++ni)
                bg[ni] = *(const bf16x8*)&Bs[wn * 64 + ni * 16 + (l & 15)][uw];
            #pragma unroll
            for (int mi = 0; mi < 4; ++mi)
                #pragma unroll
                for (int ni = 0; ni < 4; ++ni)
                    acc[mi][ni] = __builtin_amdgcn_mfma_f32_16x16x32_bf16(
                        af[mi], bg[ni], acc[mi][ni], 0, 0, 0);
        }
        __syncthreads();
    }
    float p[4] = {0, 0, 0, 0};
    #pragma unroll
    for (int mi = 0; mi < 4; ++mi) {
        int ibase = wm * 64 + mi * 16 + ((l >> 4) << 2);
        #pragma unroll
        for (int r = 0; r < 4; ++r) {
            float cv = cb[ibase + r];
            #pragma unroll
            for (int ni = 0; ni < 4; ++ni) {
                float z = acc[mi][ni][r] - cv;
                p[ni] += z * z;
            }
        }
    }
    #pragma unroll
    for (int ni = 0; ni < 4; ++ni) {
        p[ni] += __shfl_xor(p[ni], 16);
        p[ni] += __shfl_xor(p[ni], 32);
    }
    if (l < 16) {
        #pragma unroll
        for (int ni = 0; ni < 4; ++ni)
            qpart[wm][wn * 64 + ni * 16 + l] = p[ni];
    }
    __syncthreads();
    if (tid < 128) {
        float q = qpart[0][tid] + qpart[1][tid] + qpart[2][tid] + qpart[3][tid];
        float lp = -0.5f * (q + (float)D_F * LOG2PI) - ldet[mk];
        out[(size_t)(b0 + tid) * MK + mk] = wmix[mk] * lp;
    }
}

extern "C" void kernel_launch(void* const* d_in, const int* in_sizes, int n_in,
                              void* d_out, int out_size, void* d_ws, size_t ws_size,
                              hipStream_t stream) {
    const float* x     = (const float*)d_in[0];
    const float* W     = (const float*)d_in[1];
    const float* bias  = (const float*)d_in[2];
    const float* means = (const float*)d_in[3];
    const float* covs  = (const float*)d_in[4];
    const float* wts   = (const float*)d_in[5];
    float* out = (float*)d_out;

    char* ws = (char*)d_ws;
    unsigned short* dinv  = (unsigned short*)(ws);                   // 2.62 MB
    unsigned short* covsb = (unsigned short*)(ws + 4194304);         // 3.93 MB
    unsigned short* wt    = (unsigned short*)(ws + 8388608);         // 0.5 MB
    unsigned short* fb    = (unsigned short*)(ws + 8912896);         // 2 MB
    unsigned short* linv  = (unsigned short*)(ws + 11010048);        // 10.5 MB
    float* wmix = (float*)(ws + 21577728);                           // 320 B
    float* ldet = (float*)(ws + 21578048);                           // 320 B
    // cpart (320 KB) aliases wt region: wt is dead after k_feat, cpart written after.
    float* cpart = (float*)(ws + 8388608);

    k_pre<<<dim3(304), dim3(256), 0, stream>>>(W, covs, wts, wt, wmix, ldet, dinv, covsb);
    k_feat<<<dim3(64, 4), dim3(256), 0, stream>>>(x, wt, bias, fb);     // last use of wt
    k_inv_panel<<<dim3(MK, 4), dim3(256), 0, stream>>>(covsb, dinv, means, linv, cpart);
    k_gmm<<<dim3(MK, 32), dim3(512), 0, stream>>>(linv, fb, cpart, wmix, ldet, out);
}